// Round 7
// baseline (846.376 us; speedup 1.0000x reference)
//
#include <hip/hip_runtime.h>

#define NWIN 1000
#define WIN  500
#define HID  30
#define ANC  7
#define BATCH 64
#define KS   75
#define PADH 37
#define OBASE_ELEMS (BATCH*ANC*NWIN*2)   // 896000

// k1 geometry: 21 chunks of 24 positions (504 padded; 500 real)
#define CK   24
#define NCK  21

// LDS float-offset map (flat array; epilogue overlays the front)
//   x [buf][c][24 pos][68]  : buf*3264 + (c*24+p)*68 + b     [0 .. 6527]
//   W [buf][24 pos][32]     : 6528 + buf*768 + p*32 + j      [6528 .. 8063]
//   hs[ph][64 b][61]        : (ph*64+b)*61 + col  (overlay)  [0 .. 7807]
#define XB(buf,c,p,b) ((buf)*3264 + ((c)*24+(p))*68 + (b))
#define WB(buf,p,j)   (6528 + (buf)*768 + (p)*32 + (j))
#define HS(ph,b,col)  (((ph)*64+(b))*61 + (col))

__device__ __forceinline__ void gload_lds16(const float* g, float* l) {
    __builtin_amdgcn_global_load_lds(
        (const __attribute__((address_space(1))) void*)g,
        (__attribute__((address_space(3))) void*)l, 16, 0, 0);
}

// ---------------------------------------------------------------------------
// Kernel 1 (v7): identical to v6 except occupancy declaration —
// amdgpu_waves_per_eu(4) so 4 blocks/CU can be resident (v6's (256,2)
// capped residency at 2 blocks/CU -> 21.6% occupancy, latency-bound).
// lane = (bq 0..15, jq 0..3): acc[4 b][8 j][2 c]; per position one wave reads
// 2 b128 x + 2 b128 W for 64 FMA. W via global_load_lds; x staged as
// 3 float4/thread.
// ---------------------------------------------------------------------------
__global__
__attribute__((amdgpu_flat_work_group_size(256, 256)))
__attribute__((amdgpu_waves_per_eu(4)))
void k1(
        const float* __restrict__ x,
        const float* __restrict__ W1, const float* __restrict__ b1,
        const float* __restrict__ W2, const float* __restrict__ b2,
        float* __restrict__ out_base)
{
    __shared__ float smem[8064];   // 32,256 B -> 4 blocks/CU

    const int n    = blockIdx.x;
    const int t    = threadIdx.x;
    const int wid  = __builtin_amdgcn_readfirstlane(t >> 6);
    const int lane = t & 63;
    const int bq   = lane & 15;        // 4-batch group
    const int jq   = lane >> 4;        // j-quarter
    const int b0   = bq * 4;
    const int j0   = jq * 8;

    float acc[4][8][2];
#pragma unroll
    for (int i = 0; i < 4; ++i)
#pragma unroll
        for (int j = 0; j < 8; ++j) { acc[i][j][0] = 0.f; acc[i][j][1] = 0.f; }

    // x staging: granule = float4 = 2 positions x 2 channels.
    // 64 b * 12 granules = 768 per chunk -> exactly 3 per thread.
    int sb[3], sq[3];
#pragma unroll
    for (int r = 0; r < 3; ++r) {
        const int idx = t + r * 256;
        sb[r] = idx / 12;
        sq[r] = idx % 12;
    }

    const float4* __restrict__ x4 = reinterpret_cast<const float4*>(x);
    float4 xr[3];

    auto issue_x = [&](int ck) {
#pragma unroll
        for (int r = 0; r < 3; ++r) {
            int gq = ck * 12 + sq[r];          // float4 index within window row
            if (gq > 249) gq = 249;            // last-chunk OOB clamp
            xr[r] = x4[(size_t)sb[r] * 250000u + (size_t)n * 250u + gq];
        }
    };

    auto commit_x = [&](int buf, int ck) {
#pragma unroll
        for (int r = 0; r < 3; ++r) {
            const int p0 = 2 * sq[r], p1 = p0 + 1;
            const bool ok0 = (ck * CK + p0) < 500;
            const bool ok1 = (ck * CK + p1) < 500;
            const int bb = sb[r];
            smem[XB(buf, 0, p0, bb)] = ok0 ? fmaf(2.f, xr[r].x, -1.f) : 0.f;
            smem[XB(buf, 1, p0, bb)] = ok0 ? fmaf(2.f, xr[r].y, -1.f) : 0.f;
            smem[XB(buf, 0, p1, bb)] = ok1 ? fmaf(2.f, xr[r].z, -1.f) : 0.f;
            smem[XB(buf, 1, p1, bb)] = ok1 ? fmaf(2.f, xr[r].w, -1.f) : 0.f;
        }
    };

    // W chunk: 24 rows x 30 floats -> 192 16B granules into padded [24][32].
    // granule (row=t>>3, kq=t&7) reads floats row*30 + kq*4 (straddle junk
    // lands in pad slots 30/31 -> never used).
    auto issue_w = [&](int ck, int buf) {
        if (t < 192) {
            size_t off = (size_t)n * 15000u + (size_t)(ck * CK + (t >> 3)) * 30u
                       + (size_t)(t & 7) * 4u;
            if (off > 14999996u) off = 14999996u;       // tail OOB clamp
            gload_lds16(W1 + off, &smem[WB(buf, 0, 0) + (t & 192) * 4]);
        }
    };

    // ---- prologue ------------------------------------------------------
    issue_w(0, 0);
    issue_x(0);
    commit_x(0, 0);
    __syncthreads();

    // ---- main loop: 1 barrier per chunk --------------------------------
    for (int ck = 0; ck < NCK; ++ck) {
        const int cur = ck & 1, nxt = cur ^ 1;
        const bool pre = (ck < NCK - 1);
        if (pre) {
            issue_w(ck + 1, nxt);
            issue_x(ck + 1);
            __builtin_amdgcn_sched_barrier(0);   // pin issues before compute
        }

        const int pb = wid * 6;
#pragma unroll
        for (int i = 0; i < 6; ++i) {
            const int p = pb + i;
            const float4 xa = *reinterpret_cast<const float4*>(&smem[XB(cur, 0, p, b0)]);
            const float4 xb = *reinterpret_cast<const float4*>(&smem[XB(cur, 1, p, b0)]);
            const float4 w0 = *reinterpret_cast<const float4*>(&smem[WB(cur, p, j0)]);
            const float4 w1 = *reinterpret_cast<const float4*>(&smem[WB(cur, p, j0 + 4)]);
            const float xav[4] = {xa.x, xa.y, xa.z, xa.w};
            const float xbv[4] = {xb.x, xb.y, xb.z, xb.w};
            const float wv[8]  = {w0.x, w0.y, w0.z, w0.w, w1.x, w1.y, w1.z, w1.w};
#pragma unroll
            for (int ii = 0; ii < 4; ++ii)
#pragma unroll
                for (int jj = 0; jj < 8; ++jj) {
                    acc[ii][jj][0] = fmaf(xav[ii], wv[jj], acc[ii][jj][0]);
                    acc[ii][jj][1] = fmaf(xbv[ii], wv[jj], acc[ii][jj][1]);
                }
        }

        if (pre) commit_x(nxt, ck + 1);          // vmcnt waits (covered)
        __syncthreads();                         // drains gload_lds too
    }

    // ---- epilogue: reduce 4 wave-partials into hs[0] + hs[1] ------------
    if (wid < 2) {
#pragma unroll
        for (int ii = 0; ii < 4; ++ii)
#pragma unroll
            for (int jj = 0; jj < 8; ++jj) {
                const int j = j0 + jj;
                if (j < 30) {
                    smem[HS(wid, b0 + ii, j)]      = acc[ii][jj][0];
                    smem[HS(wid, b0 + ii, 30 + j)] = acc[ii][jj][1];
                }
            }
    }
    __syncthreads();
    if (wid >= 2) {
#pragma unroll
        for (int ii = 0; ii < 4; ++ii)
#pragma unroll
            for (int jj = 0; jj < 8; ++jj) {
                const int j = j0 + jj;
                if (j < 30) {
                    smem[HS(wid - 2, b0 + ii, j)]      += acc[ii][jj][0];
                    smem[HS(wid - 2, b0 + ii, 30 + j)] += acc[ii][jj][1];
                }
            }
    }
    __syncthreads();

    {   // bias + relu + TWO-PASS batch stats (64-lane butterflies) + normalize
        const int bb = t & 63;
        const int q2 = t >> 6;
        const int ch = q2 >> 1;
        const int jh = (q2 & 1) * 15;
        const float* __restrict__ b1p = b1 + n * HID + jh;
#pragma unroll
        for (int jj = 0; jj < 15; ++jj) {
            const int col = ch * 30 + jh + jj;
            float v = smem[HS(0, bb, col)] + smem[HS(1, bb, col)] + b1p[jj];
            v = fmaxf(v, 0.f);
            float s = v;
#pragma unroll
            for (int off = 32; off > 0; off >>= 1) s += __shfl_xor(s, off);
            const float mean = s * (1.f / 64.f);
            const float d = v - mean;
            float ss = d * d;
#pragma unroll
            for (int off = 32; off > 0; off >>= 1) ss += __shfl_xor(ss, off);
            const float var = ss * (1.f / 64.f);
            const float rn  = rsqrtf(var + 1e-5f);
            smem[HS(0, bb, col)] = d * rn;
        }
    }
    __syncthreads();

    // ---- GEMM2 + write out_base[b][a][n][c] -----------------------------
    const float* __restrict__ w2p = W2 + (size_t)n * (HID * ANC);
    float2* __restrict__ ob2 = reinterpret_cast<float2*>(out_base);
    for (int idx = t; idx < BATCH * ANC; idx += 256) {
        const int bb = idx / 7, a = idx - bb * 7;
        float o0 = b2[n * ANC + a], o1 = o0;
#pragma unroll
        for (int h = 0; h < HID; ++h) {
            const float wv = w2p[h * ANC + a];
            o0 = fmaf(smem[HS(0, bb, h)],      wv, o0);
            o1 = fmaf(smem[HS(0, bb, 30 + h)], wv, o1);
        }
        ob2[((size_t)bb * ANC + a) * NWIN + n] = make_float2(o0, o1);
    }
}

// ---------------------------------------------------------------------------
// Kernel 2: softmax over ANC + reflect-pad + conv (2 needed output columns)
// via sum/diff factorization (unchanged).
// ---------------------------------------------------------------------------
__global__ __launch_bounds__(256, 2) void k2(
        const float* __restrict__ out_base,
        const float* __restrict__ conv_w, const float* __restrict__ conv_b,
        float* __restrict__ out_smooth)
{
    __shared__ float2 sdl[199 * ANC];
    __shared__ float2 wael[ANC * ANC * KS];

    const int bidx = blockIdx.x;
    const int b  = bidx >> 3;
    const int ht = bidx & 7;
    const int h0 = ht * 125;
    const int t  = threadIdx.x;

    const float2* __restrict__ cw2 = reinterpret_cast<const float2*>(conv_w);
    for (int idx = t; idx < ANC * ANC * KS; idx += 256) {
        const float2 w = cw2[idx];
        wael[idx] = make_float2(w.x + w.y, w.x - w.y);
    }

    if (t < 199) {
        const int hglob = h0 - PADH + t;
        const int hm = hglob < 0 ? -hglob
                     : (hglob >= NWIN ? 2 * NWIN - 2 - hglob : hglob);
        float p[2][ANC];
#pragma unroll
        for (int c = 0; c < 2; ++c) {
            float v[ANC];
            float m = -1e30f;
#pragma unroll
            for (int a = 0; a < ANC; ++a) {
                v[a] = out_base[(((size_t)b * ANC + a) * NWIN + hm) * 2 + c];
                m = fmaxf(m, v[a]);
            }
            float s = 0.f;
#pragma unroll
            for (int a = 0; a < ANC; ++a) { v[a] = __expf(v[a] - m); s += v[a]; }
            const float inv = 1.f / s;
#pragma unroll
            for (int a = 0; a < ANC; ++a) p[c][a] = v[a] * inv;
        }
#pragma unroll
        for (int a = 0; a < ANC; ++a)
            sdl[t * ANC + a] = make_float2(p[0][a] + p[1][a], p[0][a] - p[1][a]);
    }
    __syncthreads();

    for (int idx = t; idx < ANC * 125; idx += 256) {
        const int o  = idx / 125;
        const int hl = idx % 125;
        float sa = 0.f, de = 0.f;
        const float2* __restrict__ wrow = &wael[o * ANC * KS];
#pragma unroll 1
        for (int i = 0; i < ANC; ++i) {
            const float2* __restrict__ sdp = &sdl[hl * ANC + i];
            const float2* __restrict__ wp  = &wrow[i * KS];
#pragma unroll 5
            for (int kh = 0; kh < KS; ++kh) {
                const float2 sd = sdp[kh * ANC];
                const float2 we = wp[kh];
                sa = fmaf(sd.x, we.x, sa);
                de = fmaf(sd.y, we.y, de);
            }
        }
        const float cb = conv_b[o];
        const float o0 = 0.5f * (sa - de) + cb;
        const float o1 = 0.5f * (sa + de) + cb;
        const size_t base = (((size_t)b * ANC + o) * NWIN + (h0 + hl)) * 2;
        out_smooth[base + 0] = o0;
        out_smooth[base + 1] = o1;
    }
}

extern "C" void kernel_launch(void* const* d_in, const int* in_sizes, int n_in,
                              void* d_out, int out_size, void* d_ws, size_t ws_size,
                              hipStream_t stream)
{
    const float* x      = (const float*)d_in[0];
    const float* W1     = (const float*)d_in[1];
    const float* b1     = (const float*)d_in[2];
    const float* W2     = (const float*)d_in[3];
    const float* b2     = (const float*)d_in[4];
    const float* conv_w = (const float*)d_in[5];
    const float* conv_b = (const float*)d_in[6];
    float* out = (float*)d_out;

    k1<<<dim3(NWIN), dim3(256), 0, stream>>>(x, W1, b1, W2, b2, out);
    k2<<<dim3(BATCH * 8), dim3(256), 0, stream>>>(out, conv_w, conv_b,
                                                  out + OBASE_ELEMS);
}

// Round 8
// 807.012 us; speedup vs baseline: 1.0488x; 1.0488x over previous
//
#include <hip/hip_runtime.h>

#define NWIN 1000
#define WIN  500
#define HID  30
#define ANC  7
#define BATCH 64
#define KS   75
#define PADH 37
#define OBASE_ELEMS (BATCH*ANC*NWIN*2)   // 896000

// k1 geometry: 21 chunks of 24 positions (504 padded; 500 real)
#define CK   24
#define NCK  21

// LDS float-offset map (flat array; epilogue overlays the front)
//   x [buf][c][24 pos][68]  : buf*3264 + (c*24+p)*68 + b     [0 .. 6527]
//   W [buf][24 pos][32]     : 6528 + buf*768 + p*32 + j      [6528 .. 8063]
//   hs[64 b][61]            : b*61 + col  (overlay)          [0 .. 3903]
#define XB(buf,c,p,b) ((buf)*3264 + ((c)*24+(p))*68 + (b))
#define WB(buf,p,j)   (6528 + (buf)*768 + (p)*32 + (j))
#define HS(b,col)     ((b)*61 + (col))

__device__ __forceinline__ void gload_lds16(const float* g, float* l) {
    __builtin_amdgcn_global_load_lds(
        (const __attribute__((address_space(1))) void*)g,
        (__attribute__((address_space(3))) void*)l, 16, 0, 0);
}

// ---------------------------------------------------------------------------
// Kernel 1 (v8): 32-float accumulator so the kernel fits the 64-VGPR budget
// that the w=4 residency declaration imposes (empirical laws from R3..R6:
// declared waves/EU w caps residency at w blocks/CU AND regalloc at 256/w).
// wave = (ch 0..1, ph 0..1): channel x position-half of each 24-pos chunk.
// lane = (bq 0..15, jq 0..3): acc[4 b][8 j] for its wave's (ch, 12 pos).
// Per position: 1 b128 x + 2 b128 W per 32 FMA. W via global_load_lds;
// x reg-staged as 3 float4/thread. 1 barrier per chunk, double-buffered.
// ---------------------------------------------------------------------------
__global__ __launch_bounds__(256, 4) void k1(
        const float* __restrict__ x,
        const float* __restrict__ W1, const float* __restrict__ b1,
        const float* __restrict__ W2, const float* __restrict__ b2,
        float* __restrict__ out_base)
{
    __shared__ float smem[8064];   // 32,256 B -> 4 blocks/CU (LDS cap 4.96)

    const int n    = blockIdx.x;
    const int t    = threadIdx.x;
    const int wid  = __builtin_amdgcn_readfirstlane(t >> 6);
    const int lane = t & 63;
    const int ch   = wid & 1;          // channel
    const int ph   = wid >> 1;         // position half (12 each)
    const int bq   = lane & 15;
    const int jq   = lane >> 4;
    const int b0   = bq * 4;
    const int j0   = jq * 8;

    float acc[4][8];
#pragma unroll
    for (int i = 0; i < 4; ++i)
#pragma unroll
        for (int j = 0; j < 8; ++j) acc[i][j] = 0.f;

    const float4* __restrict__ x4 = reinterpret_cast<const float4*>(x);
    float4 xr[3];

    // x staging: granule = float4 = 2 positions x 2 channels for one batch.
    // 64 b * 12 granules = 768/chunk = exactly 3 per thread.
    auto issue_x = [&](int ck) {
#pragma unroll
        for (int r = 0; r < 3; ++r) {
            const int idx = t + r * 256;
            const int bb = idx / 12, q = idx % 12;
            int gq = ck * 12 + q;
            if (gq > 249) gq = 249;            // last-chunk OOB clamp
            xr[r] = x4[(size_t)bb * 250000u + (size_t)n * 250u + gq];
        }
    };

    auto commit_x = [&](int buf, int ck) {
#pragma unroll
        for (int r = 0; r < 3; ++r) {
            const int idx = t + r * 256;
            const int bb = idx / 12, q = idx % 12;
            const int p0 = 2 * q, p1 = p0 + 1;
            const bool ok0 = (ck * CK + p0) < 500;
            const bool ok1 = (ck * CK + p1) < 500;
            smem[XB(buf, 0, p0, bb)] = ok0 ? fmaf(2.f, xr[r].x, -1.f) : 0.f;
            smem[XB(buf, 1, p0, bb)] = ok0 ? fmaf(2.f, xr[r].y, -1.f) : 0.f;
            smem[XB(buf, 0, p1, bb)] = ok1 ? fmaf(2.f, xr[r].z, -1.f) : 0.f;
            smem[XB(buf, 1, p1, bb)] = ok1 ? fmaf(2.f, xr[r].w, -1.f) : 0.f;
        }
    };

    // W chunk: 24 rows x 30 floats -> 192 16B granules into padded [24][32].
    auto issue_w = [&](int ck, int buf) {
        if (t < 192) {
            size_t off = (size_t)n * 15000u + (size_t)(ck * CK + (t >> 3)) * 30u
                       + (size_t)(t & 7) * 4u;
            if (off > 14999996u) off = 14999996u;       // tail OOB clamp
            gload_lds16(W1 + off, &smem[WB(buf, 0, 0) + (t & 192) * 4]);
        }
    };

    // ---- prologue ------------------------------------------------------
    issue_w(0, 0);
    issue_x(0);
    commit_x(0, 0);
    __syncthreads();

    // ---- main loop: 1 barrier per chunk --------------------------------
    for (int ck = 0; ck < NCK; ++ck) {
        const int cur = ck & 1, nxt = cur ^ 1;
        const bool pre = (ck < NCK - 1);
        if (pre) {
            issue_w(ck + 1, nxt);
            issue_x(ck + 1);
            __builtin_amdgcn_sched_barrier(0);   // pin issues before compute
        }

        const int pb = ph * 12;
#pragma unroll
        for (int i = 0; i < 12; ++i) {
            const int p = pb + i;
            const float4 xa = *reinterpret_cast<const float4*>(&smem[XB(cur, ch, p, b0)]);
            const float4 w0 = *reinterpret_cast<const float4*>(&smem[WB(cur, p, j0)]);
            const float4 w1 = *reinterpret_cast<const float4*>(&smem[WB(cur, p, j0 + 4)]);
            const float xav[4] = {xa.x, xa.y, xa.z, xa.w};
            const float wv[8]  = {w0.x, w0.y, w0.z, w0.w, w1.x, w1.y, w1.z, w1.w};
#pragma unroll
            for (int ii = 0; ii < 4; ++ii)
#pragma unroll
                for (int jj = 0; jj < 8; ++jj)
                    acc[ii][jj] = fmaf(xav[ii], wv[jj], acc[ii][jj]);
        }

        if (pre) commit_x(nxt, ck + 1);          // vmcnt waits (covered)
        __syncthreads();                         // drains gload_lds too
    }

    // ---- epilogue: reduce the two ph-halves into hs -------------------
    if (ph == 0) {
#pragma unroll
        for (int ii = 0; ii < 4; ++ii)
#pragma unroll
            for (int jj = 0; jj < 8; ++jj) {
                const int j = j0 + jj;
                if (j < 30) smem[HS(b0 + ii, ch * 30 + j)] = acc[ii][jj];
            }
    }
    __syncthreads();
    if (ph == 1) {
#pragma unroll
        for (int ii = 0; ii < 4; ++ii)
#pragma unroll
            for (int jj = 0; jj < 8; ++jj) {
                const int j = j0 + jj;
                if (j < 30) smem[HS(b0 + ii, ch * 30 + j)] += acc[ii][jj];
            }
    }
    __syncthreads();

    {   // bias + relu + TWO-PASS batch stats (64-lane butterflies) + normalize
        const int bb = t & 63;
        const int q2 = t >> 6;
        const int c2 = q2 >> 1;
        const int jh = (q2 & 1) * 15;
        const float* __restrict__ b1p = b1 + n * HID + jh;
#pragma unroll
        for (int jj = 0; jj < 15; ++jj) {
            const int col = c2 * 30 + jh + jj;
            float v = smem[HS(bb, col)] + b1p[jj];
            v = fmaxf(v, 0.f);
            float s = v;
#pragma unroll
            for (int off = 32; off > 0; off >>= 1) s += __shfl_xor(s, off);
            const float mean = s * (1.f / 64.f);
            const float d = v - mean;
            float ss = d * d;
#pragma unroll
            for (int off = 32; off > 0; off >>= 1) ss += __shfl_xor(ss, off);
            const float var = ss * (1.f / 64.f);
            const float rn  = rsqrtf(var + 1e-5f);
            smem[HS(bb, col)] = d * rn;
        }
    }
    __syncthreads();

    // ---- GEMM2 + write out_base[b][a][n][c] -----------------------------
    const float* __restrict__ w2p = W2 + (size_t)n * (HID * ANC);
    float2* __restrict__ ob2 = reinterpret_cast<float2*>(out_base);
    for (int idx = t; idx < BATCH * ANC; idx += 256) {
        const int bb = idx / 7, a = idx - bb * 7;
        float o0 = b2[n * ANC + a], o1 = o0;
#pragma unroll
        for (int h = 0; h < HID; ++h) {
            const float wv = w2p[h * ANC + a];
            o0 = fmaf(smem[HS(bb, h)],      wv, o0);
            o1 = fmaf(smem[HS(bb, 30 + h)], wv, o1);
        }
        ob2[((size_t)bb * ANC + a) * NWIN + n] = make_float2(o0, o1);
    }
}

// ---------------------------------------------------------------------------
// Kernel 2: softmax over ANC + reflect-pad + conv (2 needed output columns)
// via sum/diff factorization. (w=4 declaration for residency law.)
// ---------------------------------------------------------------------------
__global__ __launch_bounds__(256, 4) void k2(
        const float* __restrict__ out_base,
        const float* __restrict__ conv_w, const float* __restrict__ conv_b,
        float* __restrict__ out_smooth)
{
    __shared__ float2 sdl[199 * ANC];
    __shared__ float2 wael[ANC * ANC * KS];

    const int bidx = blockIdx.x;
    const int b  = bidx >> 3;
    const int ht = bidx & 7;
    const int h0 = ht * 125;
    const int t  = threadIdx.x;

    const float2* __restrict__ cw2 = reinterpret_cast<const float2*>(conv_w);
    for (int idx = t; idx < ANC * ANC * KS; idx += 256) {
        const float2 w = cw2[idx];
        wael[idx] = make_float2(w.x + w.y, w.x - w.y);
    }

    if (t < 199) {
        const int hglob = h0 - PADH + t;
        const int hm = hglob < 0 ? -hglob
                     : (hglob >= NWIN ? 2 * NWIN - 2 - hglob : hglob);
        float p[2][ANC];
#pragma unroll
        for (int c = 0; c < 2; ++c) {
            float v[ANC];
            float m = -1e30f;
#pragma unroll
            for (int a = 0; a < ANC; ++a) {
                v[a] = out_base[(((size_t)b * ANC + a) * NWIN + hm) * 2 + c];
                m = fmaxf(m, v[a]);
            }
            float s = 0.f;
#pragma unroll
            for (int a = 0; a < ANC; ++a) { v[a] = __expf(v[a] - m); s += v[a]; }
            const float inv = 1.f / s;
#pragma unroll
            for (int a = 0; a < ANC; ++a) p[c][a] = v[a] * inv;
        }
#pragma unroll
        for (int a = 0; a < ANC; ++a)
            sdl[t * ANC + a] = make_float2(p[0][a] + p[1][a], p[0][a] - p[1][a]);
    }
    __syncthreads();

    for (int idx = t; idx < ANC * 125; idx += 256) {
        const int o  = idx / 125;
        const int hl = idx % 125;
        float sa = 0.f, de = 0.f;
        const float2* __restrict__ wrow = &wael[o * ANC * KS];
#pragma unroll 1
        for (int i = 0; i < ANC; ++i) {
            const float2* __restrict__ sdp = &sdl[hl * ANC + i];
            const float2* __restrict__ wp  = &wrow[i * KS];
#pragma unroll 5
            for (int kh = 0; kh < KS; ++kh) {
                const float2 sd = sdp[kh * ANC];
                const float2 we = wp[kh];
                sa = fmaf(sd.x, we.x, sa);
                de = fmaf(sd.y, we.y, de);
            }
        }
        const float cb = conv_b[o];
        const float o0 = 0.5f * (sa - de) + cb;
        const float o1 = 0.5f * (sa + de) + cb;
        const size_t base = (((size_t)b * ANC + o) * NWIN + (h0 + hl)) * 2;
        out_smooth[base + 0] = o0;
        out_smooth[base + 1] = o1;
    }
}

extern "C" void kernel_launch(void* const* d_in, const int* in_sizes, int n_in,
                              void* d_out, int out_size, void* d_ws, size_t ws_size,
                              hipStream_t stream)
{
    const float* x      = (const float*)d_in[0];
    const float* W1     = (const float*)d_in[1];
    const float* b1     = (const float*)d_in[2];
    const float* W2     = (const float*)d_in[3];
    const float* b2     = (const float*)d_in[4];
    const float* conv_w = (const float*)d_in[5];
    const float* conv_b = (const float*)d_in[6];
    float* out = (float*)d_out;

    k1<<<dim3(NWIN), dim3(256), 0, stream>>>(x, W1, b1, W2, b2, out);
    k2<<<dim3(BATCH * 8), dim3(256), 0, stream>>>(out, conv_w, conv_b,
                                                  out + OBASE_ELEMS);
}

// Round 12
// 230.666 us; speedup vs baseline: 3.6693x; 3.4986x over previous
//
#include <hip/hip_runtime.h>

#define NWIN 1000
#define WIN  500
#define HID  30
#define ANC  7
#define BATCH 64
#define KS   75
#define PADH 37
#define OBASE_ELEMS (BATCH*ANC*NWIN*2)   // 896000

// k1 geometry: 21 chunks of 24 positions (504 padded; 500 real)
#define CK   24
#define NCK  21

// LDS float-offset map (flat array; epilogue overlays the front)
//   xs[buf][c][24 pos][64 b] : buf*3072 + (c*24+p)*64 + b    [0 .. 6143]
//   W [buf][24 pos][32]      : 6144 + buf*768 + p*32 + j     [6144 .. 7679]
//   hs[64 b][61]             : b*61 + col  (overlay)         [0 .. 3903]
#define XSO(buf,c,p)  ((buf)*3072 + ((c)*24+(p))*64)
#define WBASE(buf)    (6144 + (buf)*768)
#define WB(buf,p,j)   (WBASE(buf) + (p)*32 + (j))
#define HS(b,col)     ((b)*61 + (col))

__device__ __forceinline__ void gload_lds4(const float* g, float* l) {
    __builtin_amdgcn_global_load_lds(
        (const __attribute__((address_space(1))) void*)g,
        (__attribute__((address_space(3))) void*)l, 4, 0, 0);
}
__device__ __forceinline__ void gload_lds16(const float* g, float* l) {
    __builtin_amdgcn_global_load_lds(
        (const __attribute__((address_space(1))) void*)g,
        (__attribute__((address_space(3))) void*)l, 16, 0, 0);
}

// ---------------------------------------------------------------------------
// Kernel 1 (v10): v9 (zero staging registers; x AND W via global_load_lds,
// only acc[32] lives across the loop) with the W-granule clamp bug fixed:
// v9 clamped the BYTE offset per window (off>14996 -> 14996), which shifted
// the last granule of EVERY window by 2 floats and corrupted j=28,29 of
// position 499 (absmax 0.435). Now only the ROW index is clamped (tail rows
// are zeroed in LDS anyway); the row-29/30 straddle lands in pad slots.
// The final granule of the whole array reads 8B past the 60MB allocation --
// stays within the last mapped page (slack 2304B), junk lands in pads.
// ---------------------------------------------------------------------------
__global__ __launch_bounds__(256, 4) void k1(
        const float* __restrict__ x,
        const float* __restrict__ W1, const float* __restrict__ b1,
        const float* __restrict__ W2, const float* __restrict__ b2,
        float* __restrict__ out_base)
{
    __shared__ float smem[7680];   // 30,720 B

    const int n    = blockIdx.x;
    const int t    = threadIdx.x;
    const int wid  = __builtin_amdgcn_readfirstlane(t >> 6);
    const int lane = t & 63;
    const int ch   = wid & 1;          // channel
    const int ph   = wid >> 1;         // position half (12 each)
    const int bq   = lane & 15;
    const int jq   = lane >> 4;
    const int b0   = bq * 4;
    const int j0   = jq * 8;

    float acc[4][8];
#pragma unroll
    for (int i = 0; i < 4; ++i)
#pragma unroll
        for (int j = 0; j < 8; ++j) acc[i][j] = 0.f;

    // per-lane x base: lane = batch
    const float* __restrict__ gx = x + (size_t)lane * 1000000u + (size_t)n * 1000u;
    // per-thread W base for this window
    const float* __restrict__ gw = W1 + (size_t)n * 15000u;

    // x staging: 48 (c,p) pairs split across 4 waves, 12 instr each.
    // instruction (c,p): lane b reads gx[gp*2 + c] -> xs[buf][c][p][b]
    auto issue_x = [&](int ck, int buf) {
#pragma unroll
        for (int i = 0; i < 12; ++i) {
            const int idx = wid * 12 + i;       // wave-uniform
            const int p = idx >> 1, c = idx & 1;
            int gp = ck * CK + p;
            if (gp > 499) gp = 499;             // tail clamp (W zeroed instead)
            gload_lds4(gx + gp * 2 + c, &smem[XSO(buf, c, p)]);
        }
    };

    // W staging: 24 rows x 30 floats -> 192 16B granules into padded [24][32].
    // Row clamp ONLY (no byte shift): tail rows 500..503 load junk that is
    // zeroed in LDS before use; row straddle (floats 30,31) lands in pads.
    auto issue_w = [&](int ck, int buf) {
        if (t < 192) {
            int gp = ck * CK + (t >> 3);
            if (gp > 499) gp = 499;
            const size_t off = (size_t)gp * 30u + (size_t)(t & 7) * 4u;  // <= 14998
            gload_lds16(gw + off, &smem[WBASE(buf) + (t & 192) * 4]);
        }
    };

    // ---- prologue ------------------------------------------------------
    issue_w(0, 0);
    issue_x(0, 0);
    __syncthreads();   // compiler drains vmcnt before barrier -> buf0 ready

    // ---- main loop: 1 barrier per chunk --------------------------------
    for (int ck = 0; ck < NCK; ++ck) {
        const int cur = ck & 1, nxt = cur ^ 1;
        const bool pre = (ck < NCK - 1);
        if (pre) {
            issue_w(ck + 1, nxt);
            issue_x(ck + 1, nxt);
        }
        if (ck == NCK - 1) {
            // zero W rows 20..23 (= positions 500..503) of this buffer
            if (t < 128) smem[WBASE(cur) + 640 + t] = 0.f;
            __syncthreads();
        }

        const int pb = ph * 12;
#pragma unroll
        for (int i = 0; i < 12; ++i) {
            const int p = pb + i;
            const float4 xa = *reinterpret_cast<const float4*>(&smem[XSO(cur, ch, p) + b0]);
            const float4 w0 = *reinterpret_cast<const float4*>(&smem[WB(cur, p, j0)]);
            const float4 w1 = *reinterpret_cast<const float4*>(&smem[WB(cur, p, j0 + 4)]);
            const float xv0 = fmaf(2.f, xa.x, -1.f);
            const float xv1 = fmaf(2.f, xa.y, -1.f);
            const float xv2 = fmaf(2.f, xa.z, -1.f);
            const float xv3 = fmaf(2.f, xa.w, -1.f);
            const float xav[4] = {xv0, xv1, xv2, xv3};
            const float wv[8]  = {w0.x, w0.y, w0.z, w0.w, w1.x, w1.y, w1.z, w1.w};
#pragma unroll
            for (int ii = 0; ii < 4; ++ii)
#pragma unroll
                for (int jj = 0; jj < 8; ++jj)
                    acc[ii][jj] = fmaf(xav[ii], wv[jj], acc[ii][jj]);
        }

        __syncthreads();   // drains this iter's gload_lds; publishes nxt
    }

    // ---- epilogue: reduce the two ph-halves into hs ---------------------
    if (ph == 0) {
#pragma unroll
        for (int ii = 0; ii < 4; ++ii)
#pragma unroll
            for (int jj = 0; jj < 8; ++jj) {
                const int j = j0 + jj;
                if (j < 30) smem[HS(b0 + ii, ch * 30 + j)] = acc[ii][jj];
            }
    }
    __syncthreads();
    if (ph == 1) {
#pragma unroll
        for (int ii = 0; ii < 4; ++ii)
#pragma unroll
            for (int jj = 0; jj < 8; ++jj) {
                const int j = j0 + jj;
                if (j < 30) smem[HS(b0 + ii, ch * 30 + j)] += acc[ii][jj];
            }
    }
    __syncthreads();

    {   // bias + relu + two-pass batch stats (64-lane butterflies) + normalize
        const int bb = t & 63;
        const int q2 = t >> 6;
        const int c2 = q2 >> 1;
        const int jh = (q2 & 1) * 15;
        const float* __restrict__ b1p = b1 + n * HID + jh;
#pragma unroll
        for (int jj = 0; jj < 15; ++jj) {
            const int col = c2 * 30 + jh + jj;
            float v = smem[HS(bb, col)] + b1p[jj];
            v = fmaxf(v, 0.f);
            float s = v;
#pragma unroll
            for (int off = 32; off > 0; off >>= 1) s += __shfl_xor(s, off);
            const float mean = s * (1.f / 64.f);
            const float d = v - mean;
            float ss = d * d;
#pragma unroll
            for (int off = 32; off > 0; off >>= 1) ss += __shfl_xor(ss, off);
            const float var = ss * (1.f / 64.f);
            const float rn  = rsqrtf(var + 1e-5f);
            smem[HS(bb, col)] = d * rn;
        }
    }
    __syncthreads();

    // ---- GEMM2 + write out_base[b][a][n][c] -----------------------------
    const float* __restrict__ w2p = W2 + (size_t)n * (HID * ANC);
    float2* __restrict__ ob2 = reinterpret_cast<float2*>(out_base);
    for (int idx = t; idx < BATCH * ANC; idx += 256) {
        const int bb = idx / 7, a = idx - bb * 7;
        float o0 = b2[n * ANC + a], o1 = o0;
#pragma unroll
        for (int h = 0; h < HID; ++h) {
            const float wv = w2p[h * ANC + a];
            o0 = fmaf(smem[HS(bb, h)],      wv, o0);
            o1 = fmaf(smem[HS(bb, 30 + h)], wv, o1);
        }
        ob2[((size_t)bb * ANC + a) * NWIN + n] = make_float2(o0, o1);
    }
}

// ---------------------------------------------------------------------------
// Kernel 2: softmax over ANC + reflect-pad + conv (2 needed output columns)
// via sum/diff factorization. (256,2): 112-reg budget, no spill.
// ---------------------------------------------------------------------------
__global__ __launch_bounds__(256, 2) void k2(
        const float* __restrict__ out_base,
        const float* __restrict__ conv_w, const float* __restrict__ conv_b,
        float* __restrict__ out_smooth)
{
    __shared__ float2 sdl[199 * ANC];
    __shared__ float2 wael[ANC * ANC * KS];

    const int bidx = blockIdx.x;
    const int b  = bidx >> 3;
    const int ht = bidx & 7;
    const int h0 = ht * 125;
    const int t  = threadIdx.x;

    const float2* __restrict__ cw2 = reinterpret_cast<const float2*>(conv_w);
    for (int idx = t; idx < ANC * ANC * KS; idx += 256) {
        const float2 w = cw2[idx];
        wael[idx] = make_float2(w.x + w.y, w.x - w.y);
    }

    if (t < 199) {
        const int hglob = h0 - PADH + t;
        const int hm = hglob < 0 ? -hglob
                     : (hglob >= NWIN ? 2 * NWIN - 2 - hglob : hglob);
        float p[2][ANC];
#pragma unroll
        for (int c = 0; c < 2; ++c) {
            float v[ANC];
            float m = -1e30f;
#pragma unroll
            for (int a = 0; a < ANC; ++a) {
                v[a] = out_base[(((size_t)b * ANC + a) * NWIN + hm) * 2 + c];
                m = fmaxf(m, v[a]);
            }
            float s = 0.f;
#pragma unroll
            for (int a = 0; a < ANC; ++a) { v[a] = __expf(v[a] - m); s += v[a]; }
            const float inv = 1.f / s;
#pragma unroll
            for (int a = 0; a < ANC; ++a) p[c][a] = v[a] * inv;
        }
#pragma unroll
        for (int a = 0; a < ANC; ++a)
            sdl[t * ANC + a] = make_float2(p[0][a] + p[1][a], p[0][a] - p[1][a]);
    }
    __syncthreads();

    for (int idx = t; idx < ANC * 125; idx += 256) {
        const int o  = idx / 125;
        const int hl = idx % 125;
        float sa = 0.f, de = 0.f;
        const float2* __restrict__ wrow = &wael[o * ANC * KS];
#pragma unroll 1
        for (int i = 0; i < ANC; ++i) {
            const float2* __restrict__ sdp = &sdl[hl * ANC + i];
            const float2* __restrict__ wp  = &wrow[i * KS];
#pragma unroll 5
            for (int kh = 0; kh < KS; ++kh) {
                const float2 sd = sdp[kh * ANC];
                const float2 we = wp[kh];
                sa = fmaf(sd.x, we.x, sa);
                de = fmaf(sd.y, we.y, de);
            }
        }
        const float cb = conv_b[o];
        const float o0 = 0.5f * (sa - de) + cb;
        const float o1 = 0.5f * (sa + de) + cb;
        const size_t base = (((size_t)b * ANC + o) * NWIN + (h0 + hl)) * 2;
        out_smooth[base + 0] = o0;
        out_smooth[base + 1] = o1;
    }
}

extern "C" void kernel_launch(void* const* d_in, const int* in_sizes, int n_in,
                              void* d_out, int out_size, void* d_ws, size_t ws_size,
                              hipStream_t stream)
{
    const float* x      = (const float*)d_in[0];
    const float* W1     = (const float*)d_in[1];
    const float* b1     = (const float*)d_in[2];
    const float* W2     = (const float*)d_in[3];
    const float* b2     = (const float*)d_in[4];
    const float* conv_w = (const float*)d_in[5];
    const float* conv_b = (const float*)d_in[6];
    float* out = (float*)d_out;

    k1<<<dim3(NWIN), dim3(256), 0, stream>>>(x, W1, b1, W2, b2, out);
    k2<<<dim3(BATCH * 8), dim3(256), 0, stream>>>(out, conv_w, conv_b,
                                                  out + OBASE_ELEMS);
}